// Round 5
// baseline (2046.172 us; speedup 1.0000x reference)
//
#include <hip/hip_runtime.h>
#include <hip/hip_bf16.h>

#define N_NODES 100000
#define N_EDGES 1600000
#define E_TBL   200000
#define D       128
#define NREG    50000
#define P_MP    4
#define L_SUB   2
#define D_META  64
#define TM      64
#define SCALE_F 0.08838834764831845f   // 1/sqrt(128)

#define SCAN_CHUNK  512
#define SCAN_BLOCKS ((N_NODES + SCAN_CHUNK - 1) / SCAN_CHUNK)   // 196

// ---------------- bf16 helpers (storage-only precision reduction) ----------------

__device__ __forceinline__ float bf2f(unsigned int u16) {
    union { unsigned int i; float f; } v;
    v.i = u16 << 16;
    return v.f;
}
__device__ __forceinline__ unsigned int f2bf(float f) {
    union { float f; unsigned int i; } v;
    v.f = f;
    return (v.i + 0x7fffu + ((v.i >> 16) & 1u)) >> 16;   // RNE
}

// ---------------- CSR build ----------------
// 8 edges/thread: 8 independent atomics in flight (latency-bound otherwise)

__global__ __launch_bounds__(256) void k_hist(const int* __restrict__ dst,
                                              int* __restrict__ cnt) {
    int t = blockIdx.x * blockDim.x + threadIdx.x;
    int base = t * 8;
    if (base + 8 <= N_EDGES) {
        int4 d0 = *(const int4*)(dst + base);
        int4 d1 = *(const int4*)(dst + base + 4);
        atomicAdd(&cnt[d0.x], 1);
        atomicAdd(&cnt[d0.y], 1);
        atomicAdd(&cnt[d0.z], 1);
        atomicAdd(&cnt[d0.w], 1);
        atomicAdd(&cnt[d1.x], 1);
        atomicAdd(&cnt[d1.y], 1);
        atomicAdd(&cnt[d1.z], 1);
        atomicAdd(&cnt[d1.w], 1);
    } else {
        for (int e = base; e < N_EDGES; ++e) atomicAdd(&cnt[dst[e]], 1);
    }
}

__global__ __launch_bounds__(256) void k_bsum(const int* __restrict__ cnt,
                                              int* __restrict__ bsum) {
    __shared__ int red[256];
    int b = blockIdx.x, t = threadIdx.x;
    int base = b * SCAN_CHUNK + t;
    int v = 0;
    if (base < N_NODES) v += cnt[base];
    if (base + 256 < N_NODES) v += cnt[base + 256];
    red[t] = v;
    __syncthreads();
    for (int o = 128; o > 0; o >>= 1) {
        if (t < o) red[t] += red[t + o];
        __syncthreads();
    }
    if (t == 0) bsum[b] = red[0];
}

__global__ __launch_bounds__(256) void k_scan_bsum(const int* __restrict__ bsum,
                                                   int* __restrict__ ebsum) {
    __shared__ int sh[256];
    int t = threadIdx.x;
    int v = (t < SCAN_BLOCKS) ? bsum[t] : 0;
    sh[t] = v;
    __syncthreads();
    for (int o = 1; o < 256; o <<= 1) {
        int u = (t >= o) ? sh[t - o] : 0;
        __syncthreads();
        sh[t] += u;
        __syncthreads();
    }
    if (t < SCAN_BLOCKS) ebsum[t] = sh[t] - v;   // exclusive
}

__global__ __launch_bounds__(256) void k_offs(const int* __restrict__ cnt,
                                              const int* __restrict__ ebsum,
                                              int* __restrict__ offs,
                                              int* __restrict__ cursor) {
    __shared__ int pair[256];
    int b = blockIdx.x, t = threadIdx.x;
    int i0 = b * SCAN_CHUNK + 2 * t;
    int i1 = i0 + 1;
    int c0 = (i0 < N_NODES) ? cnt[i0] : 0;
    int c1 = (i1 < N_NODES) ? cnt[i1] : 0;
    int ps = c0 + c1;
    pair[t] = ps;
    __syncthreads();
    for (int o = 1; o < 256; o <<= 1) {
        int u = (t >= o) ? pair[t - o] : 0;
        __syncthreads();
        pair[t] += u;
        __syncthreads();
    }
    int off0 = ebsum[b] + pair[t] - ps;
    if (i0 < N_NODES) { offs[i0] = off0; cursor[i0] = off0; }
    if (i1 < N_NODES) { offs[i1] = off0 + c0; cursor[i1] = off0 + c0; }
    if (b == 0 && t == 0) offs[N_NODES] = N_EDGES;
}

__global__ __launch_bounds__(256) void k_scatter(const int* __restrict__ src,
                                                 const int* __restrict__ dst,
                                                 int* __restrict__ cursor,
                                                 int* __restrict__ ssrc) {
    int t = blockIdx.x * blockDim.x + threadIdx.x;
    int base = t * 8;
    if (base + 8 <= N_EDGES) {
        int4 d0 = *(const int4*)(dst + base);
        int4 d1 = *(const int4*)(dst + base + 4);
        int4 s0 = *(const int4*)(src + base);
        int4 s1 = *(const int4*)(src + base + 4);
        int p0 = atomicAdd(&cursor[d0.x], 1);
        int p1 = atomicAdd(&cursor[d0.y], 1);
        int p2 = atomicAdd(&cursor[d0.z], 1);
        int p3 = atomicAdd(&cursor[d0.w], 1);
        int p4 = atomicAdd(&cursor[d1.x], 1);
        int p5 = atomicAdd(&cursor[d1.y], 1);
        int p6 = atomicAdd(&cursor[d1.z], 1);
        int p7 = atomicAdd(&cursor[d1.w], 1);
        ssrc[p0] = s0.x;
        ssrc[p1] = s0.y;
        ssrc[p2] = s0.z;
        ssrc[p3] = s0.w;
        ssrc[p4] = s1.x;
        ssrc[p5] = s1.y;
        ssrc[p6] = s1.z;
        ssrc[p7] = s1.w;
    } else {
        for (int e = base; e < N_EDGES; ++e) {
            int pos = atomicAdd(&cursor[dst[e]], 1);
            ssrc[pos] = src[e];
        }
    }
}

// ---------------- gather x0 = bf16(E[eids]) ----------------

__global__ void k_gather(const float* __restrict__ Etab, const int* __restrict__ eids,
                         unsigned short* __restrict__ x0) {
    int i = blockIdx.x * blockDim.x + threadIdx.x;   // N_NODES * 16 (8 cols each)
    int n = i >> 4, g = i & 15;
    if (n >= N_NODES) return;
    int r = eids[n];
    const float4* srcp = (const float4*)(Etab + (size_t)r * D + g * 8);
    float4 a = srcp[0], b = srcp[1];
    uint4 o;
    o.x = f2bf(a.x) | (f2bf(a.y) << 16);
    o.y = f2bf(a.z) | (f2bf(a.w) << 16);
    o.z = f2bf(b.x) | (f2bf(b.y) << 16);
    o.w = f2bf(b.z) | (f2bf(b.w) << 16);
    *(uint4*)(x0 + (size_t)n * D + g * 8) = o;
}

// ---------------- SpMM (bf16 rows, f32 accumulate, bf16 out) ----------------

__global__ __launch_bounds__(256) void k_spmm(const unsigned short* __restrict__ x,
                                              const int* __restrict__ offs,
                                              const int* __restrict__ cnt,
                                              const int* __restrict__ ssrc,
                                              unsigned short* __restrict__ s, int nrows) {
    int wv = (blockIdx.x * blockDim.x + threadIdx.x) >> 6;
    int lane = threadIdx.x & 63;
    if (wv >= nrows) return;
    int e0 = offs[wv], e1 = offs[wv + 1];
    const unsigned int* xb = (const unsigned int*)x;   // 2 bf16 per uint, 64 per row
    float ax = 0.f, ay = 0.f;

    int e = e0;
    while (e < e1) {
        int m = min(64, e1 - e);
        int idx = (lane < m) ? ssrc[e + lane] : 0;     // coalesced index load
        int j = 0;
        for (; j + 8 <= m; j += 8) {
            int s0 = __shfl(idx, j + 0, 64);
            int s1 = __shfl(idx, j + 1, 64);
            int s2 = __shfl(idx, j + 2, 64);
            int s3 = __shfl(idx, j + 3, 64);
            int s4 = __shfl(idx, j + 4, 64);
            int s5 = __shfl(idx, j + 5, 64);
            int s6 = __shfl(idx, j + 6, 64);
            int s7 = __shfl(idx, j + 7, 64);
            unsigned int v0 = xb[(size_t)s0 * 64 + lane];
            unsigned int v1 = xb[(size_t)s1 * 64 + lane];
            unsigned int v2 = xb[(size_t)s2 * 64 + lane];
            unsigned int v3 = xb[(size_t)s3 * 64 + lane];
            unsigned int v4 = xb[(size_t)s4 * 64 + lane];
            unsigned int v5 = xb[(size_t)s5 * 64 + lane];
            unsigned int v6 = xb[(size_t)s6 * 64 + lane];
            unsigned int v7 = xb[(size_t)s7 * 64 + lane];
            ax += bf2f(v0 & 0xffffu) + bf2f(v1 & 0xffffu) + bf2f(v2 & 0xffffu) + bf2f(v3 & 0xffffu)
                + bf2f(v4 & 0xffffu) + bf2f(v5 & 0xffffu) + bf2f(v6 & 0xffffu) + bf2f(v7 & 0xffffu);
            ay += bf2f(v0 >> 16) + bf2f(v1 >> 16) + bf2f(v2 >> 16) + bf2f(v3 >> 16)
                + bf2f(v4 >> 16) + bf2f(v5 >> 16) + bf2f(v6 >> 16) + bf2f(v7 >> 16);
        }
        for (; j < m; ++j) {
            int sj = __shfl(idx, j, 64);
            unsigned int v = xb[(size_t)sj * 64 + lane];
            ax += bf2f(v & 0xffffu);
            ay += bf2f(v >> 16);
        }
        e += m;
    }

    float inv = 1.0f / (float)max(cnt[wv], 1);
    unsigned int o = f2bf(ax * inv) | (f2bf(ay * inv) << 16);
    ((unsigned int*)s)[(size_t)wv * 64 + lane] = o;
}

// ---------------- fused GEMM: out = relu(s @ Wm + x @ Wr + b), f32 math ----------------

template <bool OUT_BF16>
__global__ __launch_bounds__(256) void k_gemm(const unsigned short* __restrict__ s,
                                              const unsigned short* __restrict__ x,
                                              const float* __restrict__ Wm,
                                              const float* __restrict__ Wr,
                                              const float* __restrict__ bias,
                                              void* __restrict__ outv, int M) {
    __shared__ float As[TM][D];
    __shared__ float Ax[TM][D];
    int row0 = blockIdx.x * TM;
    int tid = threadIdx.x;

#pragma unroll
    for (int i = 0; i < 4; ++i) {
        int flat = i * 256 + tid;
        int r = flat >> 4;
        int c8 = (flat & 15) * 8;
        int gr = row0 + r;
        uint4 vs = make_uint4(0, 0, 0, 0), vx = vs;
        if (gr < M) {
            vs = *(const uint4*)(s + (size_t)gr * D + c8);
            vx = *(const uint4*)(x + (size_t)gr * D + c8);
        }
        As[r][c8 + 0] = bf2f(vs.x & 0xffffu); As[r][c8 + 1] = bf2f(vs.x >> 16);
        As[r][c8 + 2] = bf2f(vs.y & 0xffffu); As[r][c8 + 3] = bf2f(vs.y >> 16);
        As[r][c8 + 4] = bf2f(vs.z & 0xffffu); As[r][c8 + 5] = bf2f(vs.z >> 16);
        As[r][c8 + 6] = bf2f(vs.w & 0xffffu); As[r][c8 + 7] = bf2f(vs.w >> 16);
        Ax[r][c8 + 0] = bf2f(vx.x & 0xffffu); Ax[r][c8 + 1] = bf2f(vx.x >> 16);
        Ax[r][c8 + 2] = bf2f(vx.y & 0xffffu); Ax[r][c8 + 3] = bf2f(vx.y >> 16);
        Ax[r][c8 + 4] = bf2f(vx.z & 0xffffu); Ax[r][c8 + 5] = bf2f(vx.z >> 16);
        Ax[r][c8 + 6] = bf2f(vx.w & 0xffffu); Ax[r][c8 + 7] = bf2f(vx.w >> 16);
    }
    __syncthreads();

    int cg = (tid & 31) * 4;
    int rg = (tid >> 5) * 8;
    float4 acc[8];
#pragma unroll
    for (int i = 0; i < 8; ++i) acc[i] = make_float4(0, 0, 0, 0);

    for (int k = 0; k < D; k += 4) {
        float4 wm0 = *(const float4*)(Wm + (size_t)(k + 0) * D + cg);
        float4 wm1 = *(const float4*)(Wm + (size_t)(k + 1) * D + cg);
        float4 wm2 = *(const float4*)(Wm + (size_t)(k + 2) * D + cg);
        float4 wm3 = *(const float4*)(Wm + (size_t)(k + 3) * D + cg);
        float4 wr0 = *(const float4*)(Wr + (size_t)(k + 0) * D + cg);
        float4 wr1 = *(const float4*)(Wr + (size_t)(k + 1) * D + cg);
        float4 wr2 = *(const float4*)(Wr + (size_t)(k + 2) * D + cg);
        float4 wr3 = *(const float4*)(Wr + (size_t)(k + 3) * D + cg);
#pragma unroll
        for (int i = 0; i < 8; ++i) {
            float4 a = *(const float4*)&As[rg + i][k];
            float4 c = *(const float4*)&Ax[rg + i][k];
            acc[i].x += a.x * wm0.x + a.y * wm1.x + a.z * wm2.x + a.w * wm3.x
                      + c.x * wr0.x + c.y * wr1.x + c.z * wr2.x + c.w * wr3.x;
            acc[i].y += a.x * wm0.y + a.y * wm1.y + a.z * wm2.y + a.w * wm3.y
                      + c.x * wr0.y + c.y * wr1.y + c.z * wr2.y + c.w * wr3.y;
            acc[i].z += a.x * wm0.z + a.y * wm1.z + a.z * wm2.z + a.w * wm3.z
                      + c.x * wr0.z + c.y * wr1.z + c.z * wr2.z + c.w * wr3.z;
            acc[i].w += a.x * wm0.w + a.y * wm1.w + a.z * wm2.w + a.w * wm3.w
                      + c.x * wr0.w + c.y * wr1.w + c.z * wr2.w + c.w * wr3.w;
        }
    }

    float4 bv = *(const float4*)(bias + cg);
#pragma unroll
    for (int i = 0; i < 8; ++i) {
        int gr = row0 + rg + i;
        if (gr < M) {
            float ox = fmaxf(acc[i].x + bv.x, 0.f);
            float oy = fmaxf(acc[i].y + bv.y, 0.f);
            float oz = fmaxf(acc[i].z + bv.z, 0.f);
            float ow = fmaxf(acc[i].w + bv.w, 0.f);
            if (OUT_BF16) {
                uint2 o;
                o.x = f2bf(ox) | (f2bf(oy) << 16);
                o.y = f2bf(oz) | (f2bf(ow) << 16);
                *(uint2*)((unsigned short*)outv + (size_t)gr * D + cg) = o;
            } else {
                float4 o = make_float4(ox, oy, oz, ow);
                *(float4*)((float*)outv + (size_t)gr * D + cg) = o;
            }
        }
    }
}

// ---------------- query = meta @ Wq + bq ----------------

__global__ void k_query(const float* __restrict__ meta, const float* __restrict__ Wq,
                        const float* __restrict__ bq, float* __restrict__ query) {
    int t = blockIdx.x * blockDim.x + threadIdx.x;
    if (t < P_MP * D) {
        int p = t >> 7, c = t & 127;
        float acc = bq[c];
        for (int k = 0; k < D_META; ++k) acc += meta[p * D_META + k] * Wq[k * D + c];
        query[t] = acc;
    }
}

// ---------------- final: per-node softmax over metapaths ----------------

__global__ __launch_bounds__(256) void k_final(const float* __restrict__ emb,
                                               const float* __restrict__ query,
                                               float* __restrict__ out) {
    int wv = (blockIdx.x * blockDim.x + threadIdx.x) >> 6;
    int lane = threadIdx.x & 63;
    if (wv >= NREG) return;
    float2 e[4];
    float sc[4];
#pragma unroll
    for (int p = 0; p < 4; ++p) {
        e[p] = *(const float2*)(emb + ((size_t)p * NREG + wv) * D + lane * 2);
        float2 q = *(const float2*)(query + p * D + lane * 2);
        float d = e[p].x * q.x + e[p].y * q.y;
#pragma unroll
        for (int o = 32; o > 0; o >>= 1) d += __shfl_xor(d, o, 64);
        sc[p] = d * SCALE_F;
    }
    float mx = fmaxf(fmaxf(sc[0], sc[1]), fmaxf(sc[2], sc[3]));
    float w[4], sum = 0.f;
#pragma unroll
    for (int p = 0; p < 4; ++p) { w[p] = __expf(sc[p] - mx); sum += w[p]; }
    float inv = 1.f / sum;
    float ox = 0.f, oy = 0.f;
#pragma unroll
    for (int p = 0; p < 4; ++p) { ox += w[p] * inv * e[p].x; oy += w[p] * inv * e[p].y; }
    float2 o; o.x = ox; o.y = oy;
    *(float2*)(out + (size_t)wv * D + lane * 2) = o;
}

// ---------------- launch ----------------

extern "C" void kernel_launch(void* const* d_in, const int* in_sizes, int n_in,
                              void* d_out, int out_size, void* d_ws, size_t ws_size,
                              hipStream_t stream) {
    const float* Etab  = (const float*)d_in[0];
    const float* meta  = (const float*)d_in[1];
    const float* Wroot = (const float*)d_in[2];   // [4][2][128][128]
    const float* Wrel  = (const float*)d_in[3];   // [4][2][128][128]
    const float* bvec  = (const float*)d_in[4];   // [4][2][128]
    const float* Wq    = (const float*)d_in[5];   // [64][128]
    const float* bq    = (const float*)d_in[6];   // [128]
    const int* edge_index = (const int*)d_in[7];  // [4][2][1600000]
    const int* eids       = (const int*)d_in[8];  // [4][100000]
    float* out = (float*)d_out;

    char* w = (char*)d_ws;
    unsigned short* x0   = (unsigned short*)w;  w += (size_t)N_NODES * D * 2;  // 25.6 MB
    unsigned short* h1   = (unsigned short*)w;  w += (size_t)N_NODES * D * 2;  // 25.6 MB
    unsigned short* sbuf = (unsigned short*)w;  w += (size_t)N_NODES * D * 2;  // 25.6 MB
    float* emb  = (float*)w;  w += (size_t)P_MP * NREG * D * 4;                // 102.4 MB
    float* query= (float*)w;  w += 512 * 4;
    int* cnt    = (int*)w;    w += (size_t)N_NODES * 4;
    int* offs   = (int*)w;    w += (size_t)(N_NODES + 1) * 4;
    int* cursor = (int*)w;    w += (size_t)N_NODES * 4;
    int* ssrc   = (int*)w;    w += (size_t)N_EDGES * 4;
    int* bsum   = (int*)w;    w += (size_t)SCAN_BLOCKS * 4;
    int* ebsum  = (int*)w;    w += (size_t)SCAN_BLOCKS * 4;

    for (int p = 0; p < P_MP; ++p) {
        const int* src = edge_index + (size_t)p * 2 * N_EDGES;
        const int* dst = src + N_EDGES;
        const int* eid = eids + (size_t)p * N_NODES;

        hipMemsetAsync(cnt, 0, (size_t)N_NODES * 4, stream);
        k_hist<<<(N_EDGES / 8 + 255) / 256, 256, 0, stream>>>(dst, cnt);
        k_bsum<<<SCAN_BLOCKS, 256, 0, stream>>>(cnt, bsum);
        k_scan_bsum<<<1, 256, 0, stream>>>(bsum, ebsum);
        k_offs<<<SCAN_BLOCKS, 256, 0, stream>>>(cnt, ebsum, offs, cursor);
        k_scatter<<<(N_EDGES / 8 + 255) / 256, 256, 0, stream>>>(src, dst, cursor, ssrc);
        k_gather<<<(N_NODES * 16 + 255) / 256, 256, 0, stream>>>(Etab, eid, x0);

        // layer 1 (M = N_NODES)
        k_spmm<<<(N_NODES * 64 + 255) / 256, 256, 0, stream>>>(x0, offs, cnt, ssrc, sbuf, N_NODES);
        {
            const float* Wm = Wrel  + ((size_t)p * L_SUB + 0) * D * D;
            const float* Wr = Wroot + ((size_t)p * L_SUB + 0) * D * D;
            const float* bb = bvec  + ((size_t)p * L_SUB + 0) * D;
            k_gemm<true><<<(N_NODES + TM - 1) / TM, 256, 0, stream>>>(sbuf, x0, Wm, Wr, bb, h1, N_NODES);
        }
        // layer 2 (only rows < NREG are ever consumed)
        k_spmm<<<(NREG * 64 + 255) / 256, 256, 0, stream>>>(h1, offs, cnt, ssrc, sbuf, NREG);
        {
            const float* Wm = Wrel  + ((size_t)p * L_SUB + 1) * D * D;
            const float* Wr = Wroot + ((size_t)p * L_SUB + 1) * D * D;
            const float* bb = bvec  + ((size_t)p * L_SUB + 1) * D;
            k_gemm<false><<<(NREG + TM - 1) / TM, 256, 0, stream>>>(sbuf, h1, Wm, Wr, bb,
                                                                    emb + (size_t)p * NREG * D, NREG);
        }
    }

    k_query<<<2, 256, 0, stream>>>(meta, Wq, bq, query);
    k_final<<<(NREG * 64 + 255) / 256, 256, 0, stream>>>(emb, query, out);
}

// Round 6
// 1570.451 us; speedup vs baseline: 1.3029x; 1.3029x over previous
//
#include <hip/hip_runtime.h>
#include <hip/hip_bf16.h>

#define N_NODES 100000
#define N_EDGES 1600000
#define E_TBL   200000
#define D       128
#define NREG    50000
#define P_MP    4
#define L_SUB   2
#define D_META  64
#define SCALE_F 0.08838834764831845f   // 1/sqrt(128)

#define SCAN_CHUNK  512
#define SCAN_BLOCKS ((N_NODES + SCAN_CHUNK - 1) / SCAN_CHUNK)   // 196

typedef __attribute__((ext_vector_type(8))) short bf16x8;
typedef __attribute__((ext_vector_type(4))) float f32x4;

// ---------------- bf16 helpers (storage-only precision reduction) ----------------

__device__ __forceinline__ float bf2f(unsigned int u16) {
    union { unsigned int i; float f; } v;
    v.i = u16 << 16;
    return v.f;
}
__device__ __forceinline__ unsigned int f2bf(float f) {
    union { float f; unsigned int i; } v;
    v.f = f;
    return (v.i + 0x7fffu + ((v.i >> 16) & 1u)) >> 16;   // RNE
}

// ---------------- CSR build (1 edge/thread: measured better than 8-wide) ----------------

__global__ void k_hist(const int* __restrict__ dst, int* __restrict__ cnt) {
    int e = blockIdx.x * blockDim.x + threadIdx.x;
    if (e < N_EDGES) atomicAdd(&cnt[dst[e]], 1);
}

__global__ __launch_bounds__(256) void k_bsum(const int* __restrict__ cnt,
                                              int* __restrict__ bsum) {
    __shared__ int red[256];
    int b = blockIdx.x, t = threadIdx.x;
    int base = b * SCAN_CHUNK + t;
    int v = 0;
    if (base < N_NODES) v += cnt[base];
    if (base + 256 < N_NODES) v += cnt[base + 256];
    red[t] = v;
    __syncthreads();
    for (int o = 128; o > 0; o >>= 1) {
        if (t < o) red[t] += red[t + o];
        __syncthreads();
    }
    if (t == 0) bsum[b] = red[0];
}

__global__ __launch_bounds__(256) void k_scan_bsum(const int* __restrict__ bsum,
                                                   int* __restrict__ ebsum) {
    __shared__ int sh[256];
    int t = threadIdx.x;
    int v = (t < SCAN_BLOCKS) ? bsum[t] : 0;
    sh[t] = v;
    __syncthreads();
    for (int o = 1; o < 256; o <<= 1) {
        int u = (t >= o) ? sh[t - o] : 0;
        __syncthreads();
        sh[t] += u;
        __syncthreads();
    }
    if (t < SCAN_BLOCKS) ebsum[t] = sh[t] - v;   // exclusive
}

__global__ __launch_bounds__(256) void k_offs(const int* __restrict__ cnt,
                                              const int* __restrict__ ebsum,
                                              int* __restrict__ offs,
                                              int* __restrict__ cursor) {
    __shared__ int pair[256];
    int b = blockIdx.x, t = threadIdx.x;
    int i0 = b * SCAN_CHUNK + 2 * t;
    int i1 = i0 + 1;
    int c0 = (i0 < N_NODES) ? cnt[i0] : 0;
    int c1 = (i1 < N_NODES) ? cnt[i1] : 0;
    int ps = c0 + c1;
    pair[t] = ps;
    __syncthreads();
    for (int o = 1; o < 256; o <<= 1) {
        int u = (t >= o) ? pair[t - o] : 0;
        __syncthreads();
        pair[t] += u;
        __syncthreads();
    }
    int off0 = ebsum[b] + pair[t] - ps;
    if (i0 < N_NODES) { offs[i0] = off0; cursor[i0] = off0; }
    if (i1 < N_NODES) { offs[i1] = off0 + c0; cursor[i1] = off0 + c0; }
    if (b == 0 && t == 0) offs[N_NODES] = N_EDGES;
}

__global__ void k_scatter(const int* __restrict__ src, const int* __restrict__ dst,
                          int* __restrict__ cursor, int* __restrict__ ssrc) {
    int e = blockIdx.x * blockDim.x + threadIdx.x;
    if (e < N_EDGES) {
        int pos = atomicAdd(&cursor[dst[e]], 1);
        ssrc[pos] = src[e];
    }
}

// ---------------- gather x0 = bf16(E[eids]) ----------------

__global__ void k_gather(const float* __restrict__ Etab, const int* __restrict__ eids,
                         unsigned short* __restrict__ x0) {
    int i = blockIdx.x * blockDim.x + threadIdx.x;   // N_NODES * 16 (8 cols each)
    int n = i >> 4, g = i & 15;
    if (n >= N_NODES) return;
    int r = eids[n];
    const float4* srcp = (const float4*)(Etab + (size_t)r * D + g * 8);
    float4 a = srcp[0], b = srcp[1];
    uint4 o;
    o.x = f2bf(a.x) | (f2bf(a.y) << 16);
    o.y = f2bf(a.z) | (f2bf(a.w) << 16);
    o.z = f2bf(b.x) | (f2bf(b.y) << 16);
    o.w = f2bf(b.z) | (f2bf(b.w) << 16);
    *(uint4*)(x0 + (size_t)n * D + g * 8) = o;
}

// ---------------- SpMM (bf16 rows, f32 accumulate, bf16 out) ----------------

__global__ __launch_bounds__(256) void k_spmm(const unsigned short* __restrict__ x,
                                              const int* __restrict__ offs,
                                              const int* __restrict__ cnt,
                                              const int* __restrict__ ssrc,
                                              unsigned short* __restrict__ s, int nrows) {
    int wv = (blockIdx.x * blockDim.x + threadIdx.x) >> 6;
    int lane = threadIdx.x & 63;
    if (wv >= nrows) return;
    int e0 = offs[wv], e1 = offs[wv + 1];
    const unsigned int* xb = (const unsigned int*)x;   // 2 bf16 per uint, 64 per row
    float ax = 0.f, ay = 0.f;

    int e = e0;
    while (e < e1) {
        int m = min(64, e1 - e);
        int idx = (lane < m) ? ssrc[e + lane] : 0;     // coalesced index load
        int j = 0;
        for (; j + 8 <= m; j += 8) {
            int s0 = __shfl(idx, j + 0, 64);
            int s1 = __shfl(idx, j + 1, 64);
            int s2 = __shfl(idx, j + 2, 64);
            int s3 = __shfl(idx, j + 3, 64);
            int s4 = __shfl(idx, j + 4, 64);
            int s5 = __shfl(idx, j + 5, 64);
            int s6 = __shfl(idx, j + 6, 64);
            int s7 = __shfl(idx, j + 7, 64);
            unsigned int v0 = xb[(size_t)s0 * 64 + lane];
            unsigned int v1 = xb[(size_t)s1 * 64 + lane];
            unsigned int v2 = xb[(size_t)s2 * 64 + lane];
            unsigned int v3 = xb[(size_t)s3 * 64 + lane];
            unsigned int v4 = xb[(size_t)s4 * 64 + lane];
            unsigned int v5 = xb[(size_t)s5 * 64 + lane];
            unsigned int v6 = xb[(size_t)s6 * 64 + lane];
            unsigned int v7 = xb[(size_t)s7 * 64 + lane];
            ax += bf2f(v0 & 0xffffu) + bf2f(v1 & 0xffffu) + bf2f(v2 & 0xffffu) + bf2f(v3 & 0xffffu)
                + bf2f(v4 & 0xffffu) + bf2f(v5 & 0xffffu) + bf2f(v6 & 0xffffu) + bf2f(v7 & 0xffffu);
            ay += bf2f(v0 >> 16) + bf2f(v1 >> 16) + bf2f(v2 >> 16) + bf2f(v3 >> 16)
                + bf2f(v4 >> 16) + bf2f(v5 >> 16) + bf2f(v6 >> 16) + bf2f(v7 >> 16);
        }
        for (; j < m; ++j) {
            int sj = __shfl(idx, j, 64);
            unsigned int v = xb[(size_t)sj * 64 + lane];
            ax += bf2f(v & 0xffffu);
            ay += bf2f(v >> 16);
        }
        e += m;
    }

    float inv = 1.0f / (float)max(cnt[wv], 1);
    unsigned int o = f2bf(ax * inv) | (f2bf(ay * inv) << 16);
    ((unsigned int*)s)[(size_t)wv * 64 + lane] = o;
}

// ---------------- weight pre-swizzle: f32 W[128][128] -> bf16 B-frag order ----------------
// layout per matrix: [c:4][t:8][lane:64][j:8] bf16 ; element = W[32c + (lane>>4)*8 + j][16t + (lane&15)]
// mat index = ((mp*2 + layer)*2 + which), which 0 = Wm (from W_rel), 1 = Wr (from W_root)

__global__ __launch_bounds__(256) void k_wswz(const float* __restrict__ Wroot,
                                              const float* __restrict__ Wrel,
                                              unsigned short* __restrict__ wswz) {
    int gid = blockIdx.x * blockDim.x + threadIdx.x;   // 16*4*8*64 = 32768
    if (gid >= 16 * 4 * 8 * 64) return;
    int lane = gid & 63;
    int t = (gid >> 6) & 7;
    int c = (gid >> 9) & 3;
    int mat = gid >> 11;                 // 0..15
    int which = mat & 1;
    int pl = mat >> 1;                   // mp*2 + layer
    const float* W = (which == 0 ? Wrel : Wroot) + (size_t)pl * D * D;
    int k0 = c * 32 + (lane >> 4) * 8;
    int n = t * 16 + (lane & 15);
    unsigned short o[8];
#pragma unroll
    for (int j = 0; j < 8; ++j) o[j] = (unsigned short)f2bf(W[(size_t)(k0 + j) * D + n]);
    *(uint4*)(wswz + ((size_t)((mat * 4 + c) * 8 + t) * 64 + lane) * 8) = *(uint4*)o;
}

// ---------------- MFMA GEMM: out = relu(s @ Wm + x @ Wr + b) ----------------
// one wave per 16-row strip; A-frag = contiguous 16B/lane from global;
// B-frags from pre-swizzled bf16 weights (L2-resident, 32 KB each).
// 16x16x32 bf16 MFMA: A[m=lane&15][k=quad*8+j], B[k=quad*8+j][n=lane&15],
// D[m=quad*4+reg][n=lane&15]  (m89-verified mapping).

template <bool OUT_BF16>
__global__ __launch_bounds__(256) void k_mgemm(const unsigned short* __restrict__ s,
                                               const unsigned short* __restrict__ x,
                                               const unsigned short* __restrict__ wm_swz,
                                               const unsigned short* __restrict__ wr_swz,
                                               const float* __restrict__ bias,
                                               void* __restrict__ outv, int M) {
    int wid = (blockIdx.x * 256 + threadIdx.x) >> 6;
    int lane = threadIdx.x & 63;
    int row0 = wid << 4;
    if (row0 >= M) return;                  // M is a multiple of 16
    int arow = row0 + (lane & 15);
    int asub = (lane >> 4) * 8;

    union U { uint4 u; bf16x8 v; };
    f32x4 acc[8];
#pragma unroll
    for (int t = 0; t < 8; ++t) acc[t] = (f32x4){0.f, 0.f, 0.f, 0.f};

#pragma unroll
    for (int c = 0; c < 4; ++c) {
        U as, ax;
        as.u = *(const uint4*)(s + (size_t)arow * D + c * 32 + asub);
        ax.u = *(const uint4*)(x + (size_t)arow * D + c * 32 + asub);
#pragma unroll
        for (int t = 0; t < 8; ++t) {
            U bm, br;
            bm.u = *(const uint4*)(wm_swz + ((size_t)((c * 8 + t) * 64) + lane) * 8);
            br.u = *(const uint4*)(wr_swz + ((size_t)((c * 8 + t) * 64) + lane) * 8);
            acc[t] = __builtin_amdgcn_mfma_f32_16x16x32_bf16(as.v, bm.v, acc[t], 0, 0, 0);
            acc[t] = __builtin_amdgcn_mfma_f32_16x16x32_bf16(ax.v, br.v, acc[t], 0, 0, 0);
        }
    }

    int colb = lane & 15;
    int rq = (lane >> 4) * 4;
#pragma unroll
    for (int t = 0; t < 8; ++t) {
        int col = t * 16 + colb;
        float bv = bias[col];
#pragma unroll
        for (int r = 0; r < 4; ++r) {
            float v = fmaxf(acc[t][r] + bv, 0.f);
            size_t off = (size_t)(row0 + rq + r) * D + col;
            if (OUT_BF16) ((unsigned short*)outv)[off] = (unsigned short)f2bf(v);
            else          ((float*)outv)[off] = v;
        }
    }
}

// ---------------- query = meta @ Wq + bq ----------------

__global__ void k_query(const float* __restrict__ meta, const float* __restrict__ Wq,
                        const float* __restrict__ bq, float* __restrict__ query) {
    int t = blockIdx.x * blockDim.x + threadIdx.x;
    if (t < P_MP * D) {
        int p = t >> 7, c = t & 127;
        float acc = bq[c];
        for (int k = 0; k < D_META; ++k) acc += meta[p * D_META + k] * Wq[k * D + c];
        query[t] = acc;
    }
}

// ---------------- final: per-node softmax over metapaths ----------------

__global__ __launch_bounds__(256) void k_final(const float* __restrict__ emb,
                                               const float* __restrict__ query,
                                               float* __restrict__ out) {
    int wv = (blockIdx.x * blockDim.x + threadIdx.x) >> 6;
    int lane = threadIdx.x & 63;
    if (wv >= NREG) return;
    float2 e[4];
    float sc[4];
#pragma unroll
    for (int p = 0; p < 4; ++p) {
        e[p] = *(const float2*)(emb + ((size_t)p * NREG + wv) * D + lane * 2);
        float2 q = *(const float2*)(query + p * D + lane * 2);
        float d = e[p].x * q.x + e[p].y * q.y;
#pragma unroll
        for (int o = 32; o > 0; o >>= 1) d += __shfl_xor(d, o, 64);
        sc[p] = d * SCALE_F;
    }
    float mx = fmaxf(fmaxf(sc[0], sc[1]), fmaxf(sc[2], sc[3]));
    float w[4], sum = 0.f;
#pragma unroll
    for (int p = 0; p < 4; ++p) { w[p] = __expf(sc[p] - mx); sum += w[p]; }
    float inv = 1.f / sum;
    float ox = 0.f, oy = 0.f;
#pragma unroll
    for (int p = 0; p < 4; ++p) { ox += w[p] * inv * e[p].x; oy += w[p] * inv * e[p].y; }
    float2 o; o.x = ox; o.y = oy;
    *(float2*)(out + (size_t)wv * D + lane * 2) = o;
}

// ---------------- launch ----------------

extern "C" void kernel_launch(void* const* d_in, const int* in_sizes, int n_in,
                              void* d_out, int out_size, void* d_ws, size_t ws_size,
                              hipStream_t stream) {
    const float* Etab  = (const float*)d_in[0];
    const float* meta  = (const float*)d_in[1];
    const float* Wroot = (const float*)d_in[2];   // [4][2][128][128]
    const float* Wrel  = (const float*)d_in[3];   // [4][2][128][128]
    const float* bvec  = (const float*)d_in[4];   // [4][2][128]
    const float* Wq    = (const float*)d_in[5];   // [64][128]
    const float* bq    = (const float*)d_in[6];   // [128]
    const int* edge_index = (const int*)d_in[7];  // [4][2][1600000]
    const int* eids       = (const int*)d_in[8];  // [4][100000]
    float* out = (float*)d_out;

    char* w = (char*)d_ws;
    unsigned short* x0   = (unsigned short*)w;  w += (size_t)N_NODES * D * 2;  // 25.6 MB
    unsigned short* h1   = (unsigned short*)w;  w += (size_t)N_NODES * D * 2;  // 25.6 MB
    unsigned short* sbuf = (unsigned short*)w;  w += (size_t)N_NODES * D * 2;  // 25.6 MB
    float* emb  = (float*)w;  w += (size_t)P_MP * NREG * D * 4;                // 102.4 MB
    unsigned short* wswz = (unsigned short*)w;  w += (size_t)16 * D * D * 2;   // 512 KB
    float* query= (float*)w;  w += 512 * 4;
    int* cnt    = (int*)w;    w += (size_t)N_NODES * 4;
    int* offs   = (int*)w;    w += (size_t)(N_NODES + 1) * 4;
    int* cursor = (int*)w;    w += (size_t)N_NODES * 4;
    int* ssrc   = (int*)w;    w += (size_t)N_EDGES * 4;
    int* bsum   = (int*)w;    w += (size_t)SCAN_BLOCKS * 4;
    int* ebsum  = (int*)w;    w += (size_t)SCAN_BLOCKS * 4;

    k_wswz<<<128, 256, 0, stream>>>(Wroot, Wrel, wswz);

    for (int p = 0; p < P_MP; ++p) {
        const int* src = edge_index + (size_t)p * 2 * N_EDGES;
        const int* dst = src + N_EDGES;
        const int* eid = eids + (size_t)p * N_NODES;

        hipMemsetAsync(cnt, 0, (size_t)N_NODES * 4, stream);
        k_hist<<<(N_EDGES + 255) / 256, 256, 0, stream>>>(dst, cnt);
        k_bsum<<<SCAN_BLOCKS, 256, 0, stream>>>(cnt, bsum);
        k_scan_bsum<<<1, 256, 0, stream>>>(bsum, ebsum);
        k_offs<<<SCAN_BLOCKS, 256, 0, stream>>>(cnt, ebsum, offs, cursor);
        k_scatter<<<(N_EDGES + 255) / 256, 256, 0, stream>>>(src, dst, cursor, ssrc);
        k_gather<<<(N_NODES * 16 + 255) / 256, 256, 0, stream>>>(Etab, eid, x0);

        const unsigned short* wm1 = wswz + (size_t)(((p * 2 + 0) * 2 + 0)) * D * D;
        const unsigned short* wr1 = wswz + (size_t)(((p * 2 + 0) * 2 + 1)) * D * D;
        const unsigned short* wm2 = wswz + (size_t)(((p * 2 + 1) * 2 + 0)) * D * D;
        const unsigned short* wr2 = wswz + (size_t)(((p * 2 + 1) * 2 + 1)) * D * D;

        // layer 1 (M = N_NODES)
        k_spmm<<<(N_NODES * 64 + 255) / 256, 256, 0, stream>>>(x0, offs, cnt, ssrc, sbuf, N_NODES);
        k_mgemm<true><<<(N_NODES / 16 + 3) / 4, 256, 0, stream>>>(
            sbuf, x0, wm1, wr1, bvec + ((size_t)p * L_SUB + 0) * D, h1, N_NODES);

        // layer 2 (only rows < NREG are ever consumed)
        k_spmm<<<(NREG * 64 + 255) / 256, 256, 0, stream>>>(h1, offs, cnt, ssrc, sbuf, NREG);
        k_mgemm<false><<<(NREG / 16 + 3) / 4, 256, 0, stream>>>(
            sbuf, h1, wm2, wr2, bvec + ((size_t)p * L_SUB + 1) * D,
            emb + (size_t)p * NREG * D, NREG);
    }

    k_query<<<2, 256, 0, stream>>>(meta, Wq, bq, query);
    k_final<<<(NREG * 64 + 255) / 256, 256, 0, stream>>>(emb, query, out);
}

// Round 7
// 1101.950 us; speedup vs baseline: 1.8569x; 1.4252x over previous
//
#include <hip/hip_runtime.h>
#include <hip/hip_bf16.h>

#define N_NODES 100000
#define N_EDGES 1600000
#define E_TBL   200000
#define D       128
#define NREG    50000
#define P_MP    4
#define L_SUB   2
#define D_META  64
#define SCALE_F 0.08838834764831845f   // 1/sqrt(128)

// two-level counting sort geometry
#define BKT_SHIFT 9
#define BKT_NODES 512
#define NBKT      196                     // ceil(100000/512)
#define CSB       128                     // coarse-sort blocks (1.6M/128 = 12500 edges each)
#define EPB       (N_EDGES / CSB)         // 12500
#define P2N       (NBKT * CSB)            // 25088 = 98*256 exactly
#define P2B       (P2N / 256)             // 98

typedef __attribute__((ext_vector_type(8))) short bf16x8;
typedef __attribute__((ext_vector_type(4))) float f32x4;

// ---------------- bf16 helpers ----------------

__device__ __forceinline__ float bf2f(unsigned int u16) {
    union { unsigned int i; float f; } v;
    v.i = u16 << 16;
    return v.f;
}
__device__ __forceinline__ unsigned int f2bf(float f) {
    union { float f; unsigned int i; } v;
    v.f = f;
    return (v.i + 0x7fffu + ((v.i >> 16) & 1u)) >> 16;   // RNE
}

// ---------------- CSR build: two-level counting sort ----------------
// P1: per-block bucket histograms (LDS), table [bucket][block]

__global__ __launch_bounds__(256) void p1_bhist(const int* __restrict__ dst,
                                                int* __restrict__ tbl) {
    __shared__ int h[NBKT];
    int b = blockIdx.x, t = threadIdx.x;
    if (t < NBKT) h[t] = 0;
    __syncthreads();
    int e0 = b * EPB;
    for (int e = e0 + t; e < e0 + EPB; e += 256)
        atomicAdd(&h[dst[e] >> BKT_SHIFT], 1);
    __syncthreads();
    if (t < NBKT) tbl[t * CSB + b] = h[t];
}

// P2: exclusive scan of the 25088-entry table (3-kernel hierarchical, coalesced)

__global__ __launch_bounds__(256) void p2a(const int* __restrict__ tbl,
                                           int* __restrict__ bsum) {
    __shared__ int red[256];
    int b = blockIdx.x, t = threadIdx.x;
    red[t] = tbl[b * 256 + t];
    __syncthreads();
    for (int o = 128; o > 0; o >>= 1) {
        if (t < o) red[t] += red[t + o];
        __syncthreads();
    }
    if (t == 0) bsum[b] = red[0];
}

__global__ __launch_bounds__(128) void p2b(const int* __restrict__ bsum,
                                           int* __restrict__ ebsum) {
    __shared__ int sh[128];
    int t = threadIdx.x;
    int v = (t < P2B) ? bsum[t] : 0;
    sh[t] = v;
    __syncthreads();
    for (int o = 1; o < 128; o <<= 1) {
        int u = (t >= o) ? sh[t - o] : 0;
        __syncthreads();
        sh[t] += u;
        __syncthreads();
    }
    if (t < P2B) ebsum[t] = sh[t] - v;   // exclusive
}

__global__ __launch_bounds__(256) void p2c(const int* __restrict__ tbl,
                                           const int* __restrict__ ebsum,
                                           int* __restrict__ tblx,
                                           int* __restrict__ offs) {
    __shared__ int sh[256];
    int b = blockIdx.x, t = threadIdx.x;
    int v = tbl[b * 256 + t];
    sh[t] = v;
    __syncthreads();
    for (int o = 1; o < 256; o <<= 1) {
        int u = (t >= o) ? sh[t - o] : 0;
        __syncthreads();
        sh[t] += u;
        __syncthreads();
    }
    tblx[b * 256 + t] = ebsum[b] + sh[t] - v;   // exclusive
    if (b == 0 && t == 0) offs[N_NODES] = N_EDGES;
}

// P3: coarse scatter of (src,dst) pairs into bucket-contiguous regions.
// Each block owns exclusive per-bucket ranges -> no global contention,
// writes are short contiguous runs from one CU.

__global__ __launch_bounds__(256) void p3_coarse(const int* __restrict__ src,
                                                 const int* __restrict__ dst,
                                                 const int* __restrict__ tblx,
                                                 uint2* __restrict__ pairs) {
    __shared__ int lcur[NBKT];
    int b = blockIdx.x, t = threadIdx.x;
    if (t < NBKT) lcur[t] = tblx[t * CSB + b];
    __syncthreads();
    int e0 = b * EPB;
    for (int e = e0 + t; e < e0 + EPB; e += 256) {
        int d = dst[e], s = src[e];
        int pos = atomicAdd(&lcur[d >> BKT_SHIFT], 1);
        pairs[pos] = make_uint2((unsigned)s, (unsigned)d);
    }
}

// P4: one block per bucket. LDS node-histogram -> block scan -> offs/cnt,
// then LDS-cursor fine scatter of ssrc (all writes within one 32KB window, one CU).

__global__ __launch_bounds__(256) void p4_fine(const uint2* __restrict__ pairs,
                                               const int* __restrict__ tblx,
                                               int* __restrict__ offs,
                                               int* __restrict__ cnt,
                                               int* __restrict__ ssrc) {
    __shared__ int lhist[BKT_NODES];
    __shared__ int lcur[BKT_NODES];
    __shared__ int pr[256];
    int b = blockIdx.x, t = threadIdx.x;
    int nbase = b << BKT_SHIFT;
    int e0 = tblx[b * CSB];
    int e1 = (b + 1 < NBKT) ? tblx[(b + 1) * CSB] : N_EDGES;
    lhist[t] = 0;
    lhist[t + 256] = 0;
    __syncthreads();
    for (int e = e0 + t; e < e1; e += 256)
        atomicAdd(&lhist[pairs[e].y - nbase], 1);
    __syncthreads();
    int c0 = lhist[2 * t], c1 = lhist[2 * t + 1];
    int ps = c0 + c1;
    pr[t] = ps;
    __syncthreads();
    for (int o = 1; o < 256; o <<= 1) {
        int u = (t >= o) ? pr[t - o] : 0;
        __syncthreads();
        pr[t] += u;
        __syncthreads();
    }
    int ex = e0 + pr[t] - ps;                  // exclusive offset for node 2t
    lcur[2 * t] = ex;
    lcur[2 * t + 1] = ex + c0;
    int n0 = nbase + 2 * t;
    if (n0 < N_NODES)     { offs[n0] = ex;          cnt[n0] = c0; }
    if (n0 + 1 < N_NODES) { offs[n0 + 1] = ex + c0; cnt[n0 + 1] = c1; }
    __syncthreads();
    for (int e = e0 + t; e < e1; e += 256) {
        uint2 pq = pairs[e];
        int pos = atomicAdd(&lcur[pq.y - nbase], 1);
        ssrc[pos] = (int)pq.x;
    }
}

// ---------------- gather x0 = bf16(E[eids]) ----------------

__global__ void k_gather(const float* __restrict__ Etab, const int* __restrict__ eids,
                         unsigned short* __restrict__ x0) {
    int i = blockIdx.x * blockDim.x + threadIdx.x;   // N_NODES * 16 (8 cols each)
    int n = i >> 4, g = i & 15;
    if (n >= N_NODES) return;
    int r = eids[n];
    const float4* srcp = (const float4*)(Etab + (size_t)r * D + g * 8);
    float4 a = srcp[0], b = srcp[1];
    uint4 o;
    o.x = f2bf(a.x) | (f2bf(a.y) << 16);
    o.y = f2bf(a.z) | (f2bf(a.w) << 16);
    o.z = f2bf(b.x) | (f2bf(b.y) << 16);
    o.w = f2bf(b.z) | (f2bf(b.w) << 16);
    *(uint4*)(x0 + (size_t)n * D + g * 8) = o;
}

// ---------------- SpMM (bf16 rows, f32 accumulate, bf16 out) ----------------

__global__ __launch_bounds__(256) void k_spmm(const unsigned short* __restrict__ x,
                                              const int* __restrict__ offs,
                                              const int* __restrict__ cnt,
                                              const int* __restrict__ ssrc,
                                              unsigned short* __restrict__ s, int nrows) {
    int wv = (blockIdx.x * blockDim.x + threadIdx.x) >> 6;
    int lane = threadIdx.x & 63;
    if (wv >= nrows) return;
    int e0 = offs[wv], e1 = offs[wv + 1];
    const unsigned int* xb = (const unsigned int*)x;   // 2 bf16 per uint, 64 per row
    float ax = 0.f, ay = 0.f;

    int e = e0;
    while (e < e1) {
        int m = min(64, e1 - e);
        int idx = (lane < m) ? ssrc[e + lane] : 0;     // coalesced index load
        int j = 0;
        for (; j + 8 <= m; j += 8) {
            int s0 = __shfl(idx, j + 0, 64);
            int s1 = __shfl(idx, j + 1, 64);
            int s2 = __shfl(idx, j + 2, 64);
            int s3 = __shfl(idx, j + 3, 64);
            int s4 = __shfl(idx, j + 4, 64);
            int s5 = __shfl(idx, j + 5, 64);
            int s6 = __shfl(idx, j + 6, 64);
            int s7 = __shfl(idx, j + 7, 64);
            unsigned int v0 = xb[(size_t)s0 * 64 + lane];
            unsigned int v1 = xb[(size_t)s1 * 64 + lane];
            unsigned int v2 = xb[(size_t)s2 * 64 + lane];
            unsigned int v3 = xb[(size_t)s3 * 64 + lane];
            unsigned int v4 = xb[(size_t)s4 * 64 + lane];
            unsigned int v5 = xb[(size_t)s5 * 64 + lane];
            unsigned int v6 = xb[(size_t)s6 * 64 + lane];
            unsigned int v7 = xb[(size_t)s7 * 64 + lane];
            ax += bf2f(v0 & 0xffffu) + bf2f(v1 & 0xffffu) + bf2f(v2 & 0xffffu) + bf2f(v3 & 0xffffu)
                + bf2f(v4 & 0xffffu) + bf2f(v5 & 0xffffu) + bf2f(v6 & 0xffffu) + bf2f(v7 & 0xffffu);
            ay += bf2f(v0 >> 16) + bf2f(v1 >> 16) + bf2f(v2 >> 16) + bf2f(v3 >> 16)
                + bf2f(v4 >> 16) + bf2f(v5 >> 16) + bf2f(v6 >> 16) + bf2f(v7 >> 16);
        }
        for (; j < m; ++j) {
            int sj = __shfl(idx, j, 64);
            unsigned int v = xb[(size_t)sj * 64 + lane];
            ax += bf2f(v & 0xffffu);
            ay += bf2f(v >> 16);
        }
        e += m;
    }

    float inv = 1.0f / (float)max(cnt[wv], 1);
    unsigned int o = f2bf(ax * inv) | (f2bf(ay * inv) << 16);
    ((unsigned int*)s)[(size_t)wv * 64 + lane] = o;
}

// ---------------- weight pre-swizzle: f32 W[128][128] -> bf16 B-frag order ----------------

__global__ __launch_bounds__(256) void k_wswz(const float* __restrict__ Wroot,
                                              const float* __restrict__ Wrel,
                                              unsigned short* __restrict__ wswz) {
    int gid = blockIdx.x * blockDim.x + threadIdx.x;   // 16*4*8*64 = 32768
    if (gid >= 16 * 4 * 8 * 64) return;
    int lane = gid & 63;
    int t = (gid >> 6) & 7;
    int c = (gid >> 9) & 3;
    int mat = gid >> 11;                 // 0..15
    int which = mat & 1;
    int pl = mat >> 1;                   // mp*2 + layer
    const float* W = (which == 0 ? Wrel : Wroot) + (size_t)pl * D * D;
    int k0 = c * 32 + (lane >> 4) * 8;
    int n = t * 16 + (lane & 15);
    unsigned short o[8];
#pragma unroll
    for (int j = 0; j < 8; ++j) o[j] = (unsigned short)f2bf(W[(size_t)(k0 + j) * D + n]);
    *(uint4*)(wswz + ((size_t)((mat * 4 + c) * 8 + t) * 64 + lane) * 8) = *(uint4*)o;
}

// ---------------- MFMA GEMM: out = relu(s @ Wm + x @ Wr + b) ----------------

template <bool OUT_BF16>
__global__ __launch_bounds__(256) void k_mgemm(const unsigned short* __restrict__ s,
                                               const unsigned short* __restrict__ x,
                                               const unsigned short* __restrict__ wm_swz,
                                               const unsigned short* __restrict__ wr_swz,
                                               const float* __restrict__ bias,
                                               void* __restrict__ outv, int M) {
    int wid = (blockIdx.x * 256 + threadIdx.x) >> 6;
    int lane = threadIdx.x & 63;
    int row0 = wid << 4;
    if (row0 >= M) return;                  // M is a multiple of 16
    int arow = row0 + (lane & 15);
    int asub = (lane >> 4) * 8;

    union U { uint4 u; bf16x8 v; };
    f32x4 acc[8];
#pragma unroll
    for (int t = 0; t < 8; ++t) acc[t] = (f32x4){0.f, 0.f, 0.f, 0.f};

#pragma unroll
    for (int c = 0; c < 4; ++c) {
        U as, ax;
        as.u = *(const uint4*)(s + (size_t)arow * D + c * 32 + asub);
        ax.u = *(const uint4*)(x + (size_t)arow * D + c * 32 + asub);
#pragma unroll
        for (int t = 0; t < 8; ++t) {
            U bm, br;
            bm.u = *(const uint4*)(wm_swz + ((size_t)((c * 8 + t) * 64) + lane) * 8);
            br.u = *(const uint4*)(wr_swz + ((size_t)((c * 8 + t) * 64) + lane) * 8);
            acc[t] = __builtin_amdgcn_mfma_f32_16x16x32_bf16(as.v, bm.v, acc[t], 0, 0, 0);
            acc[t] = __builtin_amdgcn_mfma_f32_16x16x32_bf16(ax.v, br.v, acc[t], 0, 0, 0);
        }
    }

    int colb = lane & 15;
    int rq = (lane >> 4) * 4;
#pragma unroll
    for (int t = 0; t < 8; ++t) {
        int col = t * 16 + colb;
        float bv = bias[col];
#pragma unroll
        for (int r = 0; r < 4; ++r) {
            float v = fmaxf(acc[t][r] + bv, 0.f);
            size_t off = (size_t)(row0 + rq + r) * D + col;
            if (OUT_BF16) ((unsigned short*)outv)[off] = (unsigned short)f2bf(v);
            else          ((float*)outv)[off] = v;
        }
    }
}

// ---------------- query = meta @ Wq + bq ----------------

__global__ void k_query(const float* __restrict__ meta, const float* __restrict__ Wq,
                        const float* __restrict__ bq, float* __restrict__ query) {
    int t = blockIdx.x * blockDim.x + threadIdx.x;
    if (t < P_MP * D) {
        int p = t >> 7, c = t & 127;
        float acc = bq[c];
        for (int k = 0; k < D_META; ++k) acc += meta[p * D_META + k] * Wq[k * D + c];
        query[t] = acc;
    }
}

// ---------------- final: per-node softmax over metapaths ----------------

__global__ __launch_bounds__(256) void k_final(const float* __restrict__ emb,
                                               const float* __restrict__ query,
                                               float* __restrict__ out) {
    int wv = (blockIdx.x * blockDim.x + threadIdx.x) >> 6;
    int lane = threadIdx.x & 63;
    if (wv >= NREG) return;
    float2 e[4];
    float sc[4];
#pragma unroll
    for (int p = 0; p < 4; ++p) {
        e[p] = *(const float2*)(emb + ((size_t)p * NREG + wv) * D + lane * 2);
        float2 q = *(const float2*)(query + p * D + lane * 2);
        float d = e[p].x * q.x + e[p].y * q.y;
#pragma unroll
        for (int o = 32; o > 0; o >>= 1) d += __shfl_xor(d, o, 64);
        sc[p] = d * SCALE_F;
    }
    float mx = fmaxf(fmaxf(sc[0], sc[1]), fmaxf(sc[2], sc[3]));
    float w[4], sum = 0.f;
#pragma unroll
    for (int p = 0; p < 4; ++p) { w[p] = __expf(sc[p] - mx); sum += w[p]; }
    float inv = 1.f / sum;
    float ox = 0.f, oy = 0.f;
#pragma unroll
    for (int p = 0; p < 4; ++p) { ox += w[p] * inv * e[p].x; oy += w[p] * inv * e[p].y; }
    float2 o; o.x = ox; o.y = oy;
    *(float2*)(out + (size_t)wv * D + lane * 2) = o;
}

// ---------------- launch ----------------

extern "C" void kernel_launch(void* const* d_in, const int* in_sizes, int n_in,
                              void* d_out, int out_size, void* d_ws, size_t ws_size,
                              hipStream_t stream) {
    const float* Etab  = (const float*)d_in[0];
    const float* meta  = (const float*)d_in[1];
    const float* Wroot = (const float*)d_in[2];   // [4][2][128][128]
    const float* Wrel  = (const float*)d_in[3];   // [4][2][128][128]
    const float* bvec  = (const float*)d_in[4];   // [4][2][128]
    const float* Wq    = (const float*)d_in[5];   // [64][128]
    const float* bq    = (const float*)d_in[6];   // [128]
    const int* edge_index = (const int*)d_in[7];  // [4][2][1600000]
    const int* eids       = (const int*)d_in[8];  // [4][100000]
    float* out = (float*)d_out;

    char* w = (char*)d_ws;
    unsigned short* x0   = (unsigned short*)w;  w += (size_t)N_NODES * D * 2;  // 25.6 MB
    unsigned short* h1   = (unsigned short*)w;  w += (size_t)N_NODES * D * 2;  // 25.6 MB
    unsigned short* sbuf = (unsigned short*)w;  w += (size_t)N_NODES * D * 2;  // 25.6 MB
    float* emb  = (float*)w;  w += (size_t)P_MP * NREG * D * 4;                // 102.4 MB
    unsigned short* wswz = (unsigned short*)w;  w += (size_t)16 * D * D * 2;   // 512 KB
    float* query = (float*)w; w += 512 * 4;
    uint2* pairs = (uint2*)w; w += (size_t)N_EDGES * 8;                        // 12.8 MB
    int* tbl    = (int*)w;    w += (size_t)P2N * 4;
    int* tblx   = (int*)w;    w += (size_t)P2N * 4;
    int* p2bs   = (int*)w;    w += 128 * 4;
    int* p2eb   = (int*)w;    w += 128 * 4;
    int* cnt    = (int*)w;    w += (size_t)N_NODES * 4;
    int* offs   = (int*)w;    w += (size_t)(N_NODES + 2) * 4;
    int* ssrc   = (int*)w;    w += (size_t)N_EDGES * 4;

    k_wswz<<<128, 256, 0, stream>>>(Wroot, Wrel, wswz);

    for (int p = 0; p < P_MP; ++p) {
        const int* src = edge_index + (size_t)p * 2 * N_EDGES;
        const int* dst = src + N_EDGES;
        const int* eid = eids + (size_t)p * N_NODES;

        // CSR build via two-level counting sort (no global atomics, no write amp)
        p1_bhist<<<CSB, 256, 0, stream>>>(dst, tbl);
        p2a<<<P2B, 256, 0, stream>>>(tbl, p2bs);
        p2b<<<1, 128, 0, stream>>>(p2bs, p2eb);
        p2c<<<P2B, 256, 0, stream>>>(tbl, p2eb, tblx, offs);
        p3_coarse<<<CSB, 256, 0, stream>>>(src, dst, tblx, pairs);
        p4_fine<<<NBKT, 256, 0, stream>>>(pairs, tblx, offs, cnt, ssrc);

        k_gather<<<(N_NODES * 16 + 255) / 256, 256, 0, stream>>>(Etab, eid, x0);

        const unsigned short* wm1 = wswz + (size_t)(((p * 2 + 0) * 2 + 0)) * D * D;
        const unsigned short* wr1 = wswz + (size_t)(((p * 2 + 0) * 2 + 1)) * D * D;
        const unsigned short* wm2 = wswz + (size_t)(((p * 2 + 1) * 2 + 0)) * D * D;
        const unsigned short* wr2 = wswz + (size_t)(((p * 2 + 1) * 2 + 1)) * D * D;

        // layer 1 (M = N_NODES)
        k_spmm<<<(N_NODES * 64 + 255) / 256, 256, 0, stream>>>(x0, offs, cnt, ssrc, sbuf, N_NODES);
        k_mgemm<true><<<(N_NODES / 16 + 3) / 4, 256, 0, stream>>>(
            sbuf, x0, wm1, wr1, bvec + ((size_t)p * L_SUB + 0) * D, h1, N_NODES);

        // layer 2 (only rows < NREG are ever consumed)
        k_spmm<<<(NREG * 64 + 255) / 256, 256, 0, stream>>>(h1, offs, cnt, ssrc, sbuf, NREG);
        k_mgemm<false><<<(NREG / 16 + 3) / 4, 256, 0, stream>>>(
            sbuf, h1, wm2, wr2, bvec + ((size_t)p * L_SUB + 1) * D,
            emb + (size_t)p * NREG * D, NREG);
    }

    k_query<<<2, 256, 0, stream>>>(meta, Wq, bq, query);
    k_final<<<(NREG * 64 + 255) / 256, 256, 0, stream>>>(emb, query, out);
}